// Round 4
// baseline (527.186 us; speedup 1.0000x reference)
//
#include <hip/hip_runtime.h>
#include <hip/hip_bf16.h>

typedef unsigned short u16;
typedef __attribute__((ext_vector_type(4))) float f32x4;

#define NB   8
#define CIN  256
#define EDIM 256
#define M3   768
#define HWN  4096
#define LND  64

__device__ __forceinline__ float bf2f(u16 u){ return __uint_as_float(((unsigned)u)<<16); }
__device__ __forceinline__ u16 f2bf(float f){ __hip_bfloat16 h = __float2bfloat16(f); return *reinterpret_cast<u16*>(&h); }
__device__ __forceinline__ void bf2x2(unsigned u, float &lo, float &hi){
  lo = __uint_as_float(u<<16);
  hi = __uint_as_float(u & 0xffff0000u);
}

// ---------------- QKV 1x1 conv (fp32 in, bf16 Y out): Y[n][ch][p] = sum_c W[ch][c]*X[n][c][p] + b[ch] ----------------
__global__ __launch_bounds__(256) void k_qkv(const float* __restrict__ x, const float* __restrict__ w,
                                             const float* __restrict__ bias, u16* __restrict__ Y){
  const int n = blockIdx.z, ch0 = blockIdx.y*64, p0 = blockIdx.x*64;
  __shared__ float As[16][68];  // [kk][ch_local]
  __shared__ float Bs[16][68];  // [kk][p_local]
  const int tid = threadIdx.x, tx = tid&15, ty = tid>>4;
  float acc[4][4] = {};
  const float* xn = x + (size_t)n*CIN*HWN;
  for(int k0=0;k0<CIN;k0+=16){
    {
      int chl = tid>>2, kk4 = (tid&3)*4;
      float4 wv = *(const float4*)(w + (size_t)(ch0+chl)*CIN + k0 + kk4);
      As[kk4+0][chl] = wv.x; As[kk4+1][chl] = wv.y;
      As[kk4+2][chl] = wv.z; As[kk4+3][chl] = wv.w;
    }
    {
      int kk = tid>>4, p4 = (tid&15)*4;
      *(float4*)&Bs[kk][p4] = *(const float4*)(xn + (size_t)(k0+kk)*HWN + p0 + p4);
    }
    __syncthreads();
    #pragma unroll
    for(int kk=0;kk<16;kk++){
      f32x4 a = *(f32x4*)&As[kk][ty*4];
      f32x4 b = *(f32x4*)&Bs[kk][tx*4];
      #pragma unroll
      for(int s=0;s<4;s++)
        #pragma unroll
        for(int u=0;u<4;u++) acc[s][u] += a[s]*b[u];
    }
    __syncthreads();
  }
  #pragma unroll
  for(int s=0;s<4;s++){
    int ch = ch0 + ty*4 + s;
    float bv = bias[ch];
    ushort4 o;
    o.x = f2bf(acc[s][0]+bv); o.y = f2bf(acc[s][1]+bv);
    o.z = f2bf(acc[s][2]+bv); o.w = f2bf(acc[s][3]+bv);
    *(ushort4*)(Y + (size_t)n*M3*HWN + (size_t)ch*HWN + p0 + tx*4) = o;
  }
}

// ---------------- landmarks: mean over groups of 64 pixels, /64 scale → /4096 ----------------
__global__ void k_land(const u16* __restrict__ Y, float* __restrict__ qland, float* __restrict__ kland){
  const int l = blockIdx.x, n = blockIdx.y, e = threadIdx.x;
  const u16* base = Y + (size_t)n*M3*HWN;
  float qs=0.f, ks=0.f;
  #pragma unroll 8
  for(int m=0;m<64;m++){
    size_t off = (size_t)(l*64+m)*M3;
    qs += bf2f(base[off+e]);
    ks += bf2f(base[off+256+e]);
  }
  qland[((size_t)n*LND+l)*EDIM+e] = qs*(1.f/4096.f);
  kland[((size_t)n*LND+l)*EDIM+e] = ks*(1.f/4096.f);
}

// ---------------- Z1[n][j][i] = kland_j · q_i ; Z3[n][i][j] = qland_i · k_j ----------------
__global__ __launch_bounds__(256) void k_landgemm(const u16* __restrict__ Y, const float* __restrict__ qland,
                                                  const float* __restrict__ kland, float* __restrict__ Z1,
                                                  float* __restrict__ Z3){
  const int z = blockIdx.y, n = z>>1, which = z&1;
  const int b0 = blockIdx.x*64;
  const float* land = (which ? qland : kland) + (size_t)n*LND*EDIM;
  const int boff = which ? 256 : 0;
  float* out = (which ? Z3 : Z1) + (size_t)n*LND*HWN;
  const u16* Yb = Y + (size_t)n*M3*HWN;
  __shared__ float Ls[32][68];  // [e][a]
  __shared__ float Bs[32][68];  // [e][b]
  const int tid = threadIdx.x, tx = tid&15, ty = tid>>4;
  float acc[4][4] = {};
  for(int e0=0;e0<EDIM;e0+=32){
    {
      int a = tid>>2, e8 = (tid&3)*8;
      const float* lp = land + (size_t)a*EDIM + e0 + e8;
      float4 v0 = *(const float4*)lp, v1 = *(const float4*)(lp+4);
      Ls[e8+0][a]=v0.x; Ls[e8+1][a]=v0.y; Ls[e8+2][a]=v0.z; Ls[e8+3][a]=v0.w;
      Ls[e8+4][a]=v1.x; Ls[e8+5][a]=v1.y; Ls[e8+6][a]=v1.z; Ls[e8+7][a]=v1.w;
      const u16* bp = Yb + (size_t)(b0+a)*M3 + boff + e0 + e8;
      ushort4 u0 = *(const ushort4*)bp, u1 = *(const ushort4*)(bp+4);
      Bs[e8+0][a]=bf2f(u0.x); Bs[e8+1][a]=bf2f(u0.y); Bs[e8+2][a]=bf2f(u0.z); Bs[e8+3][a]=bf2f(u0.w);
      Bs[e8+4][a]=bf2f(u1.x); Bs[e8+5][a]=bf2f(u1.y); Bs[e8+6][a]=bf2f(u1.z); Bs[e8+7][a]=bf2f(u1.w);
    }
    __syncthreads();
    #pragma unroll
    for(int e=0;e<32;e++){
      f32x4 a = *(f32x4*)&Ls[e][ty*4];
      f32x4 b = *(f32x4*)&Bs[e][tx*4];
      #pragma unroll
      for(int s=0;s<4;s++)
        #pragma unroll
        for(int u=0;u<4;u++) acc[s][u] += a[s]*b[u];
    }
    __syncthreads();
  }
  #pragma unroll
  for(int s=0;s<4;s++){
    float4 fv = make_float4(acc[s][0],acc[s][1],acc[s][2],acc[s][3]);
    *(float4*)&out[(size_t)(ty*4+s)*HWN + b0 + tx*4] = fv;
  }
}

// ---------------- softmax of Z1 over contiguous 4096 (axis=-2 of [N,HW,L]) ----------------
__global__ void k_soft1(float* __restrict__ Z1){
  const int b = blockIdx.x, n = b>>6, j = b&63, tid = threadIdx.x;
  float* base = Z1 + ((size_t)n*LND + j)*HWN;
  float v[16];
  float m = -1e30f;
  #pragma unroll
  for(int r=0;r<16;r++){ v[r] = base[r*256 + tid]; m = fmaxf(m, v[r]); }
  #pragma unroll
  for(int o=32;o;o>>=1) m = fmaxf(m, __shfl_xor(m, o));
  __shared__ float redm[4], reds[4];
  const int wid = tid>>6;
  if((tid&63)==0) redm[wid] = m;
  __syncthreads();
  m = fmaxf(fmaxf(redm[0],redm[1]), fmaxf(redm[2],redm[3]));
  float s = 0.f;
  #pragma unroll
  for(int r=0;r<16;r++){ v[r] = __expf(v[r]-m); s += v[r]; }
  #pragma unroll
  for(int o=32;o;o>>=1) s += __shfl_xor(s, o);
  if((tid&63)==0) reds[wid] = s;
  __syncthreads();
  s = reds[0]+reds[1]+reds[2]+reds[3];
  float inv = 1.f/s;
  #pragma unroll
  for(int r=0;r<16;r++) base[r*256 + tid] = v[r]*inv;
}

// ---------------- softmax of Z3 over the 64-landmark (strided) dim ----------------
__global__ void k_soft3(float* __restrict__ Z3){
  const int n = blockIdx.y;
  const int j = blockIdx.x*256 + threadIdx.x;
  float* base = Z3 + (size_t)n*LND*HWN + j;
  float v[64];
  float m = -1e30f;
  #pragma unroll
  for(int i=0;i<64;i++){ v[i] = base[(size_t)i*HWN]; m = fmaxf(m, v[i]); }
  float s = 0.f;
  #pragma unroll
  for(int i=0;i<64;i++){ v[i] = __expf(v[i]-m); s += v[i]; }
  float inv = 1.f/s;
  #pragma unroll
  for(int i=0;i<64;i++) base[(size_t)i*HWN] = v[i]*inv;
}

// ---------------- pure fp32 VALU 64x64 matmul helper (4x4 per thread) ----------------
// NOTE: no __restrict__ — mm64(Am, Am, ...) aliases A and B intentionally.
__device__ __forceinline__ void mm64(const float* A, const float* B, int i0, int j0, float r[4][4]){
  #pragma unroll
  for(int s=0;s<4;s++)
    #pragma unroll
    for(int u=0;u<4;u++) r[s][u] = 0.f;
  for(int l0=0;l0<64;l0+=4){
    f32x4 a0 = *(const f32x4*)&A[(i0+0)*64+l0];
    f32x4 a1 = *(const f32x4*)&A[(i0+1)*64+l0];
    f32x4 a2 = *(const f32x4*)&A[(i0+2)*64+l0];
    f32x4 a3 = *(const f32x4*)&A[(i0+3)*64+l0];
    #pragma unroll
    for(int t=0;t<4;t++){
      f32x4 b = *(const f32x4*)&B[(l0+t)*64+j0];
      #pragma unroll
      for(int u=0;u<4;u++){
        r[0][u] += a0[t]*b[u];
        r[1][u] += a1[t]*b[u];
        r[2][u] += a2[t]*b[u];
        r[3][u] += a3[t]*b[u];
      }
    }
  }
}

// ---------------- k2 + Newton-Schulz pseudo-inverse, ALL fp32 VALU ----------------
__global__ __launch_bounds__(256) void k_ns(const float* __restrict__ qland, const float* __restrict__ kland,
                                            float* __restrict__ KinvT){
  __shared__ float Km[64*64];
  __shared__ float Vm[64*64];
  __shared__ float Am[64*64];
  __shared__ float Bm[64*64];
  float* sred = Am;
  const int tid = threadIdx.x, n = blockIdx.x;
  const float* qb = qland + (size_t)n*LND*EDIM;
  const float* kb = kland + (size_t)n*LND*EDIM;
  const int i0 = (tid>>4)*4, j0 = (tid&15)*4;
  float r[4][4];
  #pragma unroll
  for(int s=0;s<4;s++)
    #pragma unroll
    for(int u=0;u<4;u++) r[s][u] = 0.f;
  for(int e0=0;e0<EDIM;e0+=64){
    __syncthreads();
    {
      int a = tid>>2, e16 = (tid&3)*16;
      #pragma unroll
      for(int t=0;t<16;t+=4){
        float4 qv = *(const float4*)(qb + (size_t)a*EDIM + e0 + e16 + t);
        float4 kv = *(const float4*)(kb + (size_t)a*EDIM + e0 + e16 + t);
        Am[(e16+t+0)*64+a]=qv.x; Am[(e16+t+1)*64+a]=qv.y; Am[(e16+t+2)*64+a]=qv.z; Am[(e16+t+3)*64+a]=qv.w;
        Bm[(e16+t+0)*64+a]=kv.x; Bm[(e16+t+1)*64+a]=kv.y; Bm[(e16+t+2)*64+a]=kv.z; Bm[(e16+t+3)*64+a]=kv.w;
      }
    }
    __syncthreads();
    for(int e=0;e<64;e++){
      f32x4 a = *(f32x4*)&Am[e*64+i0];
      f32x4 b = *(f32x4*)&Bm[e*64+j0];
      #pragma unroll
      for(int s=0;s<4;s++)
        #pragma unroll
        for(int u=0;u<4;u++) r[s][u] += a[s]*b[u];
    }
  }
  __syncthreads();
  #pragma unroll
  for(int s=0;s<4;s++){
    f32x4 v = {r[s][0], r[s][1], r[s][2], r[s][3]};
    *(f32x4*)&Km[(i0+s)*64 + j0] = v;
  }
  __syncthreads();
  if(tid < 64){
    int j = tid;
    float m = -1e30f;
    for(int i=0;i<64;i++) m = fmaxf(m, Km[i*64+j]);
    float ssum = 0.f;
    for(int i=0;i<64;i++) ssum += __expf(Km[i*64+j]-m);
    float inv = 1.f/ssum, cs = 0.f;
    for(int i=0;i<64;i++){
      float kv = __expf(Km[i*64+j]-m)*inv;
      Km[i*64+j] = kv;
      cs += fabsf(kv);
    }
    sred[j] = cs;
  }
  __syncthreads();
  if(tid < 64){
    int i = tid; float rs = 0.f;
    for(int j=0;j<64;j++) rs += fabsf(Km[i*64+j]);
    sred[64+i] = rs;
  }
  __syncthreads();
  if(tid == 0){
    float v0=-1e30f, vi=-1e30f;
    for(int t=0;t<64;t++){ v0 = fmaxf(v0, sred[t]); vi = fmaxf(vi, sred[64+t]); }
    sred[128] = 1.f/(v0*vi);
  }
  __syncthreads();
  {
    float sc = sred[128];
    #pragma unroll
    for(int s=0;s<4;s++)
      #pragma unroll
      for(int u=0;u<4;u++) Vm[(i0+s)*64 + j0+u] = Km[(j0+u)*64 + i0+s]*sc;   // V = K^T * sc
  }
  __syncthreads();
  for(int it=0; it<6; it++){
    mm64(Km, Vm, i0, j0, r);                  // KV = K*V
    #pragma unroll
    for(int s=0;s<4;s++){
      f32x4 v = {r[s][0], r[s][1], r[s][2], r[s][3]};
      *(f32x4*)&Am[(i0+s)*64 + j0] = v;
    }
    __syncthreads();
    mm64(Am, Am, i0, j0, r);                  // KV*KV
    #pragma unroll
    for(int s=0;s<4;s++)
      #pragma unroll
      for(int u=0;u<4;u++) Bm[(i0+s)*64+j0+u] = 7.f*Am[(i0+s)*64+j0+u] - r[s][u];   // T1 = KV*(7I-KV)
    __syncthreads();
    mm64(Am, Bm, i0, j0, r);                  // KV*T1
    __syncthreads();
    #pragma unroll
    for(int s=0;s<4;s++)
      #pragma unroll
      for(int u=0;u<4;u++) Bm[(i0+s)*64+j0+u] = 15.f*Am[(i0+s)*64+j0+u] - r[s][u];  // T2 = KV*(15I-T1)
    __syncthreads();
    mm64(Vm, Bm, i0, j0, r);                  // V*T2
    __syncthreads();
    #pragma unroll
    for(int s=0;s<4;s++)
      #pragma unroll
      for(int u=0;u<4;u++) Vm[(i0+s)*64+j0+u] = 0.25f*(13.f*Vm[(i0+s)*64+j0+u] - r[s][u]);
    __syncthreads();
  }
  #pragma unroll
  for(int u=0;u<4;u++){
    int col = j0+u;
    f32x4 fo = { Vm[(i0+0)*64+col], Vm[(i0+1)*64+col], Vm[(i0+2)*64+col], Vm[(i0+3)*64+col] };
    *(f32x4*)&KinvT[(size_t)n*4096 + (size_t)col*64 + i0] = fo;
  }
}

// ---------------- partial k3@v over j-chunks of 128: part[n][kc][64][256] ----------------
#define NSTR 72
__global__ __launch_bounds__(256) void k_f(const float* __restrict__ Z3, const u16* __restrict__ Y,
                                           float* __restrict__ part){
  const int kc = blockIdx.x, n = blockIdx.y, tid = threadIdx.x;
  const int jb = kc*128;
  __shared__ u16 k3T[128*NSTR];
  const float* z3b = Z3 + (size_t)n*LND*HWN;
  {
    int ibase = (tid>>5)*8, j4 = (tid&31)*4;
    #pragma unroll
    for(int r=0;r<8;r++){
      int i = ibase + r;
      float4 v = *(const float4*)&z3b[(size_t)i*HWN + jb + j4];
      k3T[(j4+0)*NSTR + i] = f2bf(v.x);
      k3T[(j4+1)*NSTR + i] = f2bf(v.y);
      k3T[(j4+2)*NSTR + i] = f2bf(v.z);
      k3T[(j4+3)*NSTR + i] = f2bf(v.w);
    }
  }
  __syncthreads();
  const int i0 = (tid>>4)*4, e0 = (tid&15)*16;
  const u16* Yb = Y + (size_t)n*M3*HWN;
  float acc[4][16] = {};
  for(int j=0;j<128;j++){
    ushort4 av = *(const ushort4*)&k3T[(size_t)j*NSTR + i0];
    float a0 = bf2f(av.x), a1 = bf2f(av.y), a2 = bf2f(av.z), a3 = bf2f(av.w);
    const u16* vp = Yb + (size_t)(jb+j)*M3 + 512 + e0;
    uint4 U0 = *(const uint4*)vp;
    uint4 U1 = *(const uint4*)(vp+8);
    float bv[16];
    bf2x2(U0.x, bv[0], bv[1]);  bf2x2(U0.y, bv[2], bv[3]);
    bf2x2(U0.z, bv[4], bv[5]);  bf2x2(U0.w, bv[6], bv[7]);
    bf2x2(U1.x, bv[8], bv[9]);  bf2x2(U1.y, bv[10], bv[11]);
    bf2x2(U1.z, bv[12], bv[13]); bf2x2(U1.w, bv[14], bv[15]);
    #pragma unroll
    for(int u=0;u<16;u++){
      acc[0][u] += a0*bv[u];
      acc[1][u] += a1*bv[u];
      acc[2][u] += a2*bv[u];
      acc[3][u] += a3*bv[u];
    }
  }
  float* pb = part + ((size_t)n*32 + kc)*LND*EDIM;
  #pragma unroll
  for(int s=0;s<4;s++)
    #pragma unroll
    for(int t=0;t<16;t+=4){
      float4 fv = make_float4(acc[s][t],acc[s][t+1],acc[s][t+2],acc[s][t+3]);
      *(float4*)&pb[(size_t)(i0+s)*EDIM + e0 + t] = fv;
    }
}

__global__ void k_fred(const float* __restrict__ part, float* __restrict__ B3){
  const int idx = blockIdx.x*256 + threadIdx.x;   // [n][i][e] = 131072
  const int n = idx >> 14, rem = idx & 16383;
  const float* p = part + (size_t)n*32*16384 + rem;
  float s = 0.f;
  #pragma unroll
  for(int kc=0;kc<32;kc++) s += p[(size_t)kc*16384];
  B3[idx] = s;
}

// ---------------- C2[j][e] = sum_l Kinv[j][l]*B3[l][e] (Kinv via KinvT) ----------------
__global__ __launch_bounds__(256) void k_c2(const float* __restrict__ KinvT, const float* __restrict__ B3,
                                            float* __restrict__ C2){
  const int eb = blockIdx.x*64, n = blockIdx.y, tid = threadIdx.x;
  __shared__ float KT[64][68];   // [l][j]
  __shared__ float Bs2[64][68];  // [l][e]
  {
    int l = tid>>2, o16 = (tid&3)*16;
    const float* kp = KinvT + (size_t)n*4096 + l*64 + o16;
    const float* bp = B3 + ((size_t)n*LND + l)*EDIM + eb + o16;
    #pragma unroll
    for(int t=0;t<16;t+=4){
      *(float4*)&KT[l][o16+t]  = *(const float4*)(kp+t);
      *(float4*)&Bs2[l][o16+t] = *(const float4*)(bp+t);
    }
  }
  __syncthreads();
  const int j0 = (tid>>4)*4, u0 = (tid&15)*4;
  float acc[4][4] = {};
  #pragma unroll 8
  for(int l=0;l<64;l++){
    f32x4 a = *(f32x4*)&KT[l][j0];
    f32x4 b = *(f32x4*)&Bs2[l][u0];
    #pragma unroll
    for(int s=0;s<4;s++)
      #pragma unroll
      for(int u=0;u<4;u++) acc[s][u] += a[s]*b[u];
  }
  #pragma unroll
  for(int s=0;s<4;s++){
    float4 fv = make_float4(acc[s][0],acc[s][1],acc[s][2],acc[s][3]);
    *(float4*)&C2[((size_t)n*LND + j0+s)*EDIM + eb + u0] = fv;
  }
}

// ---------------- out[i][e] = sum_j k1t[j][i]*C2[j][e] + v[i][e] (fp32) ----------------
__global__ __launch_bounds__(256) void k_out(const float* __restrict__ Z1, const float* __restrict__ C2,
                                             const u16* __restrict__ Y, float* __restrict__ OM){
  const int ib = blockIdx.x*64, n = blockIdx.y, tid = threadIdx.x;
  __shared__ float K1s[64][68];     // [j][i_local]
  __shared__ u16 C2s[64*264];       // bf16 [j][e]
  {
    int j = tid>>2, i16 = (tid&3)*16;
    const float* zp = Z1 + ((size_t)n*LND + j)*HWN + ib + i16;
    #pragma unroll
    for(int t=0;t<16;t+=4) *(float4*)&K1s[j][i16+t] = *(const float4*)(zp+t);
    int e64 = (tid&3)*64;
    const float* cp = C2 + ((size_t)n*LND + j)*EDIM + e64;
    #pragma unroll
    for(int t=0;t<64;t+=4){
      float4 v = *(const float4*)(cp+t);
      C2s[j*264 + e64+t+0] = f2bf(v.x);
      C2s[j*264 + e64+t+1] = f2bf(v.y);
      C2s[j*264 + e64+t+2] = f2bf(v.z);
      C2s[j*264 + e64+t+3] = f2bf(v.w);
    }
  }
  __syncthreads();
  const int i0 = (tid>>4)*4, e0 = (tid&15)*16;
  float acc[4][16] = {};
  for(int j=0;j<64;j++){
    f32x4 a = *(f32x4*)&K1s[j][i0];
    const u16* cb = &C2s[j*264 + e0];
    uint4 U0 = *(const uint4*)cb;
    uint4 U1 = *(const uint4*)(cb+8);
    float bv[16];
    bf2x2(U0.x, bv[0], bv[1]);  bf2x2(U0.y, bv[2], bv[3]);
    bf2x2(U0.z, bv[4], bv[5]);  bf2x2(U0.w, bv[6], bv[7]);
    bf2x2(U1.x, bv[8], bv[9]);  bf2x2(U1.y, bv[10], bv[11]);
    bf2x2(U1.z, bv[12], bv[13]); bf2x2(U1.w, bv[14], bv[15]);
    #pragma unroll
    for(int u=0;u<16;u++){
      acc[0][u] += a[0]*bv[u];
      acc[1][u] += a[1]*bv[u];
      acc[2][u] += a[2]*bv[u];
      acc[3][u] += a[3]*bv[u];
    }
  }
  const u16* Yb = Y + (size_t)n*M3*HWN;
  float* ob = OM + (size_t)n*HWN*EDIM;
  #pragma unroll
  for(int s=0;s<4;s++){
    int i = ib + i0 + s;
    const u16* vp = Yb + (size_t)i*M3 + 512 + e0;
    uint4 U0 = *(const uint4*)vp, U1 = *(const uint4*)(vp+8);
    float vv[16];
    bf2x2(U0.x, vv[0], vv[1]);  bf2x2(U0.y, vv[2], vv[3]);
    bf2x2(U0.z, vv[4], vv[5]);  bf2x2(U0.w, vv[6], vv[7]);
    bf2x2(U1.x, vv[8], vv[9]);  bf2x2(U1.y, vv[10], vv[11]);
    bf2x2(U1.z, vv[12], vv[13]); bf2x2(U1.w, vv[14], vv[15]);
    #pragma unroll
    for(int t=0;t<16;t+=4){
      float4 fv = make_float4(acc[s][t]+vv[t], acc[s][t+1]+vv[t+1], acc[s][t+2]+vv[t+2], acc[s][t+3]+vv[t+3]);
      *(float4*)&ob[(size_t)i*EDIM + e0 + t] = fv;
    }
  }
}

// ---------------- final proj (fp32 in/out): out[n][co][p] = sum_e Wout[co][e]*OMview[e][p] + b[co] ----------------
__global__ __launch_bounds__(256) void k_proj(const float* __restrict__ OM, const float* __restrict__ w,
                                              const float* __restrict__ bias, float* __restrict__ out){
  const int n = blockIdx.z, co0 = blockIdx.y*64, p0 = blockIdx.x*64;
  __shared__ float As[16][68];
  __shared__ float Bs[16][68];
  const int tid = threadIdx.x, tx = tid&15, ty = tid>>4;
  float acc[4][4] = {};
  const float* Ob = OM + (size_t)n*HWN*EDIM;
  for(int k0=0;k0<EDIM;k0+=16){
    {
      int chl = tid>>2, kk4 = (tid&3)*4;
      float4 wv = *(const float4*)(w + (size_t)(co0+chl)*EDIM + k0 + kk4);
      As[kk4+0][chl]=wv.x; As[kk4+1][chl]=wv.y;
      As[kk4+2][chl]=wv.z; As[kk4+3][chl]=wv.w;
    }
    {
      int kk = tid>>4, p4 = (tid&15)*4;
      *(float4*)&Bs[kk][p4] = *(const float4*)&Ob[(size_t)(k0+kk)*HWN + p0 + p4];
    }
    __syncthreads();
    #pragma unroll
    for(int kk=0;kk<16;kk++){
      f32x4 a = *(f32x4*)&As[kk][ty*4];
      f32x4 b = *(f32x4*)&Bs[kk][tx*4];
      #pragma unroll
      for(int s=0;s<4;s++)
        #pragma unroll
        for(int u=0;u<4;u++) acc[s][u] += a[s]*b[u];
    }
    __syncthreads();
  }
  #pragma unroll
  for(int s=0;s<4;s++){
    int co = co0 + ty*4 + s;
    float bv = bias[co];
    float4 o = make_float4(acc[s][0]+bv, acc[s][1]+bv, acc[s][2]+bv, acc[s][3]+bv);
    *(float4*)(out + (size_t)n*EDIM*HWN + (size_t)co*HWN + p0 + tx*4) = o;
  }
}

extern "C" void kernel_launch(void* const* d_in, const int* in_sizes, int n_in,
                              void* d_out, int out_size, void* d_ws, size_t ws_size,
                              hipStream_t stream){
  (void)out_size; (void)ws_size;
  // Inputs are FP32 per the reference's setup_inputs (jnp.float32).
  // Resolve by element count (pairwise distinct) to be order-robust.
  const float* x     = (const float*)d_in[0];
  const float* w_qkv = (const float*)d_in[1];
  const float* b_qkv = (const float*)d_in[2];
  const float* w_out = (const float*)d_in[3];
  const float* b_out = (const float*)d_in[4];
  for(int i=0;i<n_in;i++){
    switch(in_sizes[i]){
      case 8388608: x     = (const float*)d_in[i]; break;  // 8*256*64*64
      case 196608:  w_qkv = (const float*)d_in[i]; break;  // 768*256
      case 768:     b_qkv = (const float*)d_in[i]; break;
      case 65536:   w_out = (const float*)d_in[i]; break;  // 256*256
      case 256:     b_out = (const float*)d_in[i]; break;
      default: break;
    }
  }
  float* out = (float*)d_out;
  char* ws = (char*)d_ws;

  u16*   Y     = (u16*)(ws + 0);              // 50,331,648 B  bf16 [8][768*4096]
  float* qland = (float*)(ws + 50331648);     //    524,288 B
  float* kland = (float*)(ws + 50855936);     //    524,288 B
  float* Z1    = (float*)(ws + 51380224);     //  8,388,608 B  [8][64][4096]
  float* Z3    = (float*)(ws + 59768832);     //  8,388,608 B  [8][64][4096]
  float* KinvT = (float*)(ws + 68157440);     //    131,072 B  [8][64][64]
  float* part  = (float*)(ws + 68288512);     // 16,777,216 B  [8][32][64][256]
  float* B3    = (float*)(ws + 85065728);     //    524,288 B
  float* C2    = (float*)(ws + 85590016);     //    524,288 B
  float* OM    = (float*)(ws + 86114304);     // 33,554,432 B  fp32 [8][4096][256]

  k_qkv    <<<dim3(64,12,8), 256, 0, stream>>>(x, w_qkv, b_qkv, Y);
  k_land   <<<dim3(64,8),    256, 0, stream>>>(Y, qland, kland);
  k_landgemm<<<dim3(64,16),  256, 0, stream>>>(Y, qland, kland, Z1, Z3);
  k_soft1  <<<dim3(512),     256, 0, stream>>>(Z1);
  k_soft3  <<<dim3(16,8),    256, 0, stream>>>(Z3);
  k_ns     <<<dim3(8),       256, 0, stream>>>(qland, kland, KinvT);
  k_f      <<<dim3(32,8),    256, 0, stream>>>(Z3, Y, part);
  k_fred   <<<dim3(512),     256, 0, stream>>>(part, B3);
  k_c2     <<<dim3(4,8),     256, 0, stream>>>(KinvT, B3, C2);
  k_out    <<<dim3(64,8),    256, 0, stream>>>(Z1, C2, Y, OM);
  k_proj   <<<dim3(64,4,8),  256, 0, stream>>>(OM, w_out, b_out, out);
}

// Round 5
// 442.640 us; speedup vs baseline: 1.1910x; 1.1910x over previous
//
#include <hip/hip_runtime.h>
#include <hip/hip_bf16.h>

typedef unsigned short u16;
typedef __attribute__((ext_vector_type(4))) float f32x4;
typedef __attribute__((ext_vector_type(8))) short short8;

#define NB   8
#define CIN  256
#define EDIM 256
#define M3   768
#define HWN  4096
#define LND  64
#define KS   264   // LDS row stride (bf16 elems): 528B, 16B-aligned, conflict-floor

__device__ __forceinline__ float bf2f(u16 u){ return __uint_as_float(((unsigned)u)<<16); }
__device__ __forceinline__ u16 f2bf(float f){ __hip_bfloat16 h = __float2bfloat16(f); return *reinterpret_cast<u16*>(&h); }
__device__ __forceinline__ void bf2x2(unsigned u, float &lo, float &hi){
  lo = __uint_as_float(u<<16);
  hi = __uint_as_float(u & 0xffff0000u);
}

// ---------------- QKV 1x1 conv via bf16 MFMA: Y[n][ch][p] = sum_c W[ch][c]*X[n][c][p] + b[ch] ----------
// grid(12 ch-tiles, 64 p-tiles, 8 n); ch-tile fastest so X tile stays L2-hot across consecutive blocks.
__global__ __launch_bounds__(256) void k_qkv(const float* __restrict__ x, const float* __restrict__ w,
                                             const float* __restrict__ bias, u16* __restrict__ Y){
  const int ch0 = blockIdx.x*64, p0 = blockIdx.y*64, n = blockIdx.z;
  __shared__ u16 Abf[64*KS];   // A[m=ch_local][k=c] row-major
  __shared__ u16 Bbf[64*KS];   // B^T: [n=p_local][k=c]
  const int tid = threadIdx.x;
  { // stage A: W rows, fp32 -> bf16
    int r = tid>>2, c0 = (tid&3)*64;
    const float* wp = w + (size_t)(ch0+r)*CIN + c0;
    u16* ap = &Abf[r*KS + c0];
    #pragma unroll
    for(int t=0;t<64;t+=8){
      float4 v0 = *(const float4*)(wp+t);
      float4 v1 = *(const float4*)(wp+t+4);
      ushort4 o0, o1;
      o0.x=f2bf(v0.x); o0.y=f2bf(v0.y); o0.z=f2bf(v0.z); o0.w=f2bf(v0.w);
      o1.x=f2bf(v1.x); o1.y=f2bf(v1.y); o1.z=f2bf(v1.z); o1.w=f2bf(v1.w);
      *(ushort4*)(ap+t)   = o0;
      *(ushort4*)(ap+t+4) = o1;
    }
  }
  { // stage B transposed: thread = channel row k, scatter 64 p's
    const float* xp = x + (size_t)n*CIN*HWN + (size_t)tid*HWN + p0;
    #pragma unroll
    for(int t=0;t<64;t+=4){
      float4 v = *(const float4*)(xp+t);
      Bbf[(t+0)*KS + tid] = f2bf(v.x);
      Bbf[(t+1)*KS + tid] = f2bf(v.y);
      Bbf[(t+2)*KS + tid] = f2bf(v.z);
      Bbf[(t+3)*KS + tid] = f2bf(v.w);
    }
  }
  __syncthreads();
  const int wv = tid>>6, c = tid&15, q = (tid>>4)&3;
  f32x4 acc[4];
  #pragma unroll
  for(int t=0;t<4;t++){ acc[t][0]=0.f; acc[t][1]=0.f; acc[t][2]=0.f; acc[t][3]=0.f; }
  for(int kt=0; kt<8; kt++){
    short8 a = *(const short8*)&Abf[(16*wv + c)*KS + kt*32 + q*8];
    #pragma unroll
    for(int t=0;t<4;t++){
      short8 b = *(const short8*)&Bbf[(16*t + c)*KS + kt*32 + q*8];
      acc[t] = __builtin_amdgcn_mfma_f32_16x16x32_bf16(a, b, acc[t], 0, 0, 0);
    }
  }
  float bv[4];
  #pragma unroll
  for(int r=0;r<4;r++) bv[r] = bias[ch0 + 16*wv + 4*q + r];
  u16* Yb = Y + (size_t)n*M3*HWN;
  #pragma unroll
  for(int t=0;t<4;t++)
    #pragma unroll
    for(int r=0;r<4;r++){
      int row = 16*wv + 4*q + r, col = 16*t + c;
      Yb[(size_t)(ch0+row)*HWN + p0 + col] = f2bf(acc[t][r] + bv[r]);
    }
}

// ---------------- landmarks: mean over groups of 64 pixels, /64 scale → /4096 ----------------
__global__ void k_land(const u16* __restrict__ Y, float* __restrict__ qland, float* __restrict__ kland){
  const int l = blockIdx.x, n = blockIdx.y, e = threadIdx.x;
  const u16* base = Y + (size_t)n*M3*HWN;
  float qs=0.f, ks=0.f;
  #pragma unroll 8
  for(int m=0;m<64;m++){
    size_t off = (size_t)(l*64+m)*M3;
    qs += bf2f(base[off+e]);
    ks += bf2f(base[off+256+e]);
  }
  qland[((size_t)n*LND+l)*EDIM+e] = qs*(1.f/4096.f);
  kland[((size_t)n*LND+l)*EDIM+e] = ks*(1.f/4096.f);
}

// ---------------- Z1[n][j][i] = kland_j · q_i ; Z3[n][i][j] = qland_i · k_j ----------------
__global__ __launch_bounds__(256) void k_landgemm(const u16* __restrict__ Y, const float* __restrict__ qland,
                                                  const float* __restrict__ kland, float* __restrict__ Z1,
                                                  float* __restrict__ Z3){
  const int z = blockIdx.y, n = z>>1, which = z&1;
  const int b0 = blockIdx.x*64;
  const float* land = (which ? qland : kland) + (size_t)n*LND*EDIM;
  const int boff = which ? 256 : 0;
  float* out = (which ? Z3 : Z1) + (size_t)n*LND*HWN;
  const u16* Yb = Y + (size_t)n*M3*HWN;
  __shared__ float Ls[32][68];  // [e][a]
  __shared__ float Bs[32][68];  // [e][b]
  const int tid = threadIdx.x, tx = tid&15, ty = tid>>4;
  float acc[4][4] = {};
  for(int e0=0;e0<EDIM;e0+=32){
    {
      int a = tid>>2, e8 = (tid&3)*8;
      const float* lp = land + (size_t)a*EDIM + e0 + e8;
      float4 v0 = *(const float4*)lp, v1 = *(const float4*)(lp+4);
      Ls[e8+0][a]=v0.x; Ls[e8+1][a]=v0.y; Ls[e8+2][a]=v0.z; Ls[e8+3][a]=v0.w;
      Ls[e8+4][a]=v1.x; Ls[e8+5][a]=v1.y; Ls[e8+6][a]=v1.z; Ls[e8+7][a]=v1.w;
      const u16* bp = Yb + (size_t)(b0+a)*M3 + boff + e0 + e8;
      ushort4 u0 = *(const ushort4*)bp, u1 = *(const ushort4*)(bp+4);
      Bs[e8+0][a]=bf2f(u0.x); Bs[e8+1][a]=bf2f(u0.y); Bs[e8+2][a]=bf2f(u0.z); Bs[e8+3][a]=bf2f(u0.w);
      Bs[e8+4][a]=bf2f(u1.x); Bs[e8+5][a]=bf2f(u1.y); Bs[e8+6][a]=bf2f(u1.z); Bs[e8+7][a]=bf2f(u1.w);
    }
    __syncthreads();
    #pragma unroll
    for(int e=0;e<32;e++){
      f32x4 a = *(f32x4*)&Ls[e][ty*4];
      f32x4 b = *(f32x4*)&Bs[e][tx*4];
      #pragma unroll
      for(int s=0;s<4;s++)
        #pragma unroll
        for(int u=0;u<4;u++) acc[s][u] += a[s]*b[u];
    }
    __syncthreads();
  }
  #pragma unroll
  for(int s=0;s<4;s++){
    float4 fv = make_float4(acc[s][0],acc[s][1],acc[s][2],acc[s][3]);
    *(float4*)&out[(size_t)(ty*4+s)*HWN + b0 + tx*4] = fv;
  }
}

// ---------------- softmax of Z1 over contiguous 4096 (axis=-2 of [N,HW,L]) ----------------
__global__ void k_soft1(float* __restrict__ Z1){
  const int b = blockIdx.x, n = b>>6, j = b&63, tid = threadIdx.x;
  float* base = Z1 + ((size_t)n*LND + j)*HWN;
  float v[16];
  float m = -1e30f;
  #pragma unroll
  for(int r=0;r<16;r++){ v[r] = base[r*256 + tid]; m = fmaxf(m, v[r]); }
  #pragma unroll
  for(int o=32;o;o>>=1) m = fmaxf(m, __shfl_xor(m, o));
  __shared__ float redm[4], reds[4];
  const int wid = tid>>6;
  if((tid&63)==0) redm[wid] = m;
  __syncthreads();
  m = fmaxf(fmaxf(redm[0],redm[1]), fmaxf(redm[2],redm[3]));
  float s = 0.f;
  #pragma unroll
  for(int r=0;r<16;r++){ v[r] = __expf(v[r]-m); s += v[r]; }
  #pragma unroll
  for(int o=32;o;o>>=1) s += __shfl_xor(s, o);
  if((tid&63)==0) reds[wid] = s;
  __syncthreads();
  s = reds[0]+reds[1]+reds[2]+reds[3];
  float inv = 1.f/s;
  #pragma unroll
  for(int r=0;r<16;r++) base[r*256 + tid] = v[r]*inv;
}

// ---------------- softmax of Z3 over the 64-landmark (strided) dim ----------------
__global__ void k_soft3(float* __restrict__ Z3){
  const int n = blockIdx.y;
  const int j = blockIdx.x*256 + threadIdx.x;
  float* base = Z3 + (size_t)n*LND*HWN + j;
  float v[64];
  float m = -1e30f;
  #pragma unroll
  for(int i=0;i<64;i++){ v[i] = base[(size_t)i*HWN]; m = fmaxf(m, v[i]); }
  float s = 0.f;
  #pragma unroll
  for(int i=0;i<64;i++){ v[i] = __expf(v[i]-m); s += v[i]; }
  float inv = 1.f/s;
  #pragma unroll
  for(int i=0;i<64;i++) base[(size_t)i*HWN] = v[i]*inv;
}

// ---------------- pure fp32 VALU 64x64 matmul helper (4x4 per thread) ----------------
__device__ __forceinline__ void mm64(const float* A, const float* B, int i0, int j0, float r[4][4]){
  #pragma unroll
  for(int s=0;s<4;s++)
    #pragma unroll
    for(int u=0;u<4;u++) r[s][u] = 0.f;
  for(int l0=0;l0<64;l0+=4){
    f32x4 a0 = *(const f32x4*)&A[(i0+0)*64+l0];
    f32x4 a1 = *(const f32x4*)&A[(i0+1)*64+l0];
    f32x4 a2 = *(const f32x4*)&A[(i0+2)*64+l0];
    f32x4 a3 = *(const f32x4*)&A[(i0+3)*64+l0];
    #pragma unroll
    for(int t=0;t<4;t++){
      f32x4 b = *(const f32x4*)&B[(l0+t)*64+j0];
      #pragma unroll
      for(int u=0;u<4;u++){
        r[0][u] += a0[t]*b[u];
        r[1][u] += a1[t]*b[u];
        r[2][u] += a2[t]*b[u];
        r[3][u] += a3[t]*b[u];
      }
    }
  }
}

// ---------------- k2 + Newton-Schulz pseudo-inverse, ALL fp32 VALU ----------------
__global__ __launch_bounds__(256) void k_ns(const float* __restrict__ qland, const float* __restrict__ kland,
                                            float* __restrict__ KinvT){
  __shared__ float Km[64*64];
  __shared__ float Vm[64*64];
  __shared__ float Am[64*64];
  __shared__ float Bm[64*64];
  float* sred = Am;
  const int tid = threadIdx.x, n = blockIdx.x;
  const float* qb = qland + (size_t)n*LND*EDIM;
  const float* kb = kland + (size_t)n*LND*EDIM;
  const int i0 = (tid>>4)*4, j0 = (tid&15)*4;
  float r[4][4];
  #pragma unroll
  for(int s=0;s<4;s++)
    #pragma unroll
    for(int u=0;u<4;u++) r[s][u] = 0.f;
  for(int e0=0;e0<EDIM;e0+=64){
    __syncthreads();
    {
      int a = tid>>2, e16 = (tid&3)*16;
      #pragma unroll
      for(int t=0;t<16;t+=4){
        float4 qv = *(const float4*)(qb + (size_t)a*EDIM + e0 + e16 + t);
        float4 kv = *(const float4*)(kb + (size_t)a*EDIM + e0 + e16 + t);
        Am[(e16+t+0)*64+a]=qv.x; Am[(e16+t+1)*64+a]=qv.y; Am[(e16+t+2)*64+a]=qv.z; Am[(e16+t+3)*64+a]=qv.w;
        Bm[(e16+t+0)*64+a]=kv.x; Bm[(e16+t+1)*64+a]=kv.y; Bm[(e16+t+2)*64+a]=kv.z; Bm[(e16+t+3)*64+a]=kv.w;
      }
    }
    __syncthreads();
    for(int e=0;e<64;e++){
      f32x4 a = *(f32x4*)&Am[e*64+i0];
      f32x4 b = *(f32x4*)&Bm[e*64+j0];
      #pragma unroll
      for(int s=0;s<4;s++)
        #pragma unroll
        for(int u=0;u<4;u++) r[s][u] += a[s]*b[u];
    }
  }
  __syncthreads();
  #pragma unroll
  for(int s=0;s<4;s++){
    f32x4 v = {r[s][0], r[s][1], r[s][2], r[s][3]};
    *(f32x4*)&Km[(i0+s)*64 + j0] = v;
  }
  __syncthreads();
  if(tid < 64){
    int j = tid;
    float m = -1e30f;
    for(int i=0;i<64;i++) m = fmaxf(m, Km[i*64+j]);
    float ssum = 0.f;
    for(int i=0;i<64;i++) ssum += __expf(Km[i*64+j]-m);
    float inv = 1.f/ssum, cs = 0.f;
    for(int i=0;i<64;i++){
      float kv = __expf(Km[i*64+j]-m)*inv;
      Km[i*64+j] = kv;
      cs += fabsf(kv);
    }
    sred[j] = cs;
  }
  __syncthreads();
  if(tid < 64){
    int i = tid; float rs = 0.f;
    for(int j=0;j<64;j++) rs += fabsf(Km[i*64+j]);
    sred[64+i] = rs;
  }
  __syncthreads();
  if(tid == 0){
    float v0=-1e30f, vi=-1e30f;
    for(int t=0;t<64;t++){ v0 = fmaxf(v0, sred[t]); vi = fmaxf(vi, sred[64+t]); }
    sred[128] = 1.f/(v0*vi);
  }
  __syncthreads();
  {
    float sc = sred[128];
    #pragma unroll
    for(int s=0;s<4;s++)
      #pragma unroll
      for(int u=0;u<4;u++) Vm[(i0+s)*64 + j0+u] = Km[(j0+u)*64 + i0+s]*sc;   // V = K^T * sc
  }
  __syncthreads();
  for(int it=0; it<6; it++){
    mm64(Km, Vm, i0, j0, r);                  // KV = K*V
    #pragma unroll
    for(int s=0;s<4;s++){
      f32x4 v = {r[s][0], r[s][1], r[s][2], r[s][3]};
      *(f32x4*)&Am[(i0+s)*64 + j0] = v;
    }
    __syncthreads();
    mm64(Am, Am, i0, j0, r);                  // KV*KV
    #pragma unroll
    for(int s=0;s<4;s++)
      #pragma unroll
      for(int u=0;u<4;u++) Bm[(i0+s)*64+j0+u] = 7.f*Am[(i0+s)*64+j0+u] - r[s][u];   // T1
    __syncthreads();
    mm64(Am, Bm, i0, j0, r);                  // KV*T1
    __syncthreads();
    #pragma unroll
    for(int s=0;s<4;s++)
      #pragma unroll
      for(int u=0;u<4;u++) Bm[(i0+s)*64+j0+u] = 15.f*Am[(i0+s)*64+j0+u] - r[s][u];  // T2
    __syncthreads();
    mm64(Vm, Bm, i0, j0, r);                  // V*T2
    __syncthreads();
    #pragma unroll
    for(int s=0;s<4;s++)
      #pragma unroll
      for(int u=0;u<4;u++) Vm[(i0+s)*64+j0+u] = 0.25f*(13.f*Vm[(i0+s)*64+j0+u] - r[s][u]);
    __syncthreads();
  }
  #pragma unroll
  for(int u=0;u<4;u++){
    int col = j0+u;
    f32x4 fo = { Vm[(i0+0)*64+col], Vm[(i0+1)*64+col], Vm[(i0+2)*64+col], Vm[(i0+3)*64+col] };
    *(f32x4*)&KinvT[(size_t)n*4096 + (size_t)col*64 + i0] = fo;
  }
}

// ---------------- partial k3@v over j-chunks of 128: part[n][kc][64][256] ----------------
#define NSTR 72
__global__ __launch_bounds__(256) void k_f(const float* __restrict__ Z3, const u16* __restrict__ Y,
                                           float* __restrict__ part){
  const int kc = blockIdx.x, n = blockIdx.y, tid = threadIdx.x;
  const int jb = kc*128;
  __shared__ u16 k3T[128*NSTR];
  const float* z3b = Z3 + (size_t)n*LND*HWN;
  {
    int ibase = (tid>>5)*8, j4 = (tid&31)*4;
    #pragma unroll
    for(int r=0;r<8;r++){
      int i = ibase + r;
      float4 v = *(const float4*)&z3b[(size_t)i*HWN + jb + j4];
      k3T[(j4+0)*NSTR + i] = f2bf(v.x);
      k3T[(j4+1)*NSTR + i] = f2bf(v.y);
      k3T[(j4+2)*NSTR + i] = f2bf(v.z);
      k3T[(j4+3)*NSTR + i] = f2bf(v.w);
    }
  }
  __syncthreads();
  const int i0 = (tid>>4)*4, e0 = (tid&15)*16;
  const u16* Yb = Y + (size_t)n*M3*HWN;
  float acc[4][16] = {};
  for(int j=0;j<128;j++){
    ushort4 av = *(const ushort4*)&k3T[(size_t)j*NSTR + i0];
    float a0 = bf2f(av.x), a1 = bf2f(av.y), a2 = bf2f(av.z), a3 = bf2f(av.w);
    const u16* vp = Yb + (size_t)(jb+j)*M3 + 512 + e0;
    uint4 U0 = *(const uint4*)vp;
    uint4 U1 = *(const uint4*)(vp+8);
    float bv[16];
    bf2x2(U0.x, bv[0], bv[1]);  bf2x2(U0.y, bv[2], bv[3]);
    bf2x2(U0.z, bv[4], bv[5]);  bf2x2(U0.w, bv[6], bv[7]);
    bf2x2(U1.x, bv[8], bv[9]);  bf2x2(U1.y, bv[10], bv[11]);
    bf2x2(U1.z, bv[12], bv[13]); bf2x2(U1.w, bv[14], bv[15]);
    #pragma unroll
    for(int u=0;u<16;u++){
      acc[0][u] += a0*bv[u];
      acc[1][u] += a1*bv[u];
      acc[2][u] += a2*bv[u];
      acc[3][u] += a3*bv[u];
    }
  }
  float* pb = part + ((size_t)n*32 + kc)*LND*EDIM;
  #pragma unroll
  for(int s=0;s<4;s++)
    #pragma unroll
    for(int t=0;t<16;t+=4){
      float4 fv = make_float4(acc[s][t],acc[s][t+1],acc[s][t+2],acc[s][t+3]);
      *(float4*)&pb[(size_t)(i0+s)*EDIM + e0 + t] = fv;
    }
}

__global__ void k_fred(const float* __restrict__ part, float* __restrict__ B3){
  const int idx = blockIdx.x*256 + threadIdx.x;   // [n][i][e] = 131072
  const int n = idx >> 14, rem = idx & 16383;
  const float* p = part + (size_t)n*32*16384 + rem;
  float s = 0.f;
  #pragma unroll
  for(int kc=0;kc<32;kc++) s += p[(size_t)kc*16384];
  B3[idx] = s;
}

// ---------------- C2[j][e] = sum_l Kinv[j][l]*B3[l][e] ----------------
__global__ __launch_bounds__(256) void k_c2(const float* __restrict__ KinvT, const float* __restrict__ B3,
                                            float* __restrict__ C2){
  const int eb = blockIdx.x*64, n = blockIdx.y, tid = threadIdx.x;
  __shared__ float KT[64][68];   // [l][j]
  __shared__ float Bs2[64][68];  // [l][e]
  {
    int l = tid>>2, o16 = (tid&3)*16;
    const float* kp = KinvT + (size_t)n*4096 + l*64 + o16;
    const float* bp = B3 + ((size_t)n*LND + l)*EDIM + eb + o16;
    #pragma unroll
    for(int t=0;t<16;t+=4){
      *(float4*)&KT[l][o16+t]  = *(const float4*)(kp+t);
      *(float4*)&Bs2[l][o16+t] = *(const float4*)(bp+t);
    }
  }
  __syncthreads();
  const int j0 = (tid>>4)*4, u0 = (tid&15)*4;
  float acc[4][4] = {};
  #pragma unroll 8
  for(int l=0;l<64;l++){
    f32x4 a = *(f32x4*)&KT[l][j0];
    f32x4 b = *(f32x4*)&Bs2[l][u0];
    #pragma unroll
    for(int s=0;s<4;s++)
      #pragma unroll
      for(int u=0;u<4;u++) acc[s][u] += a[s]*b[u];
  }
  #pragma unroll
  for(int s=0;s<4;s++){
    float4 fv = make_float4(acc[s][0],acc[s][1],acc[s][2],acc[s][3]);
    *(float4*)&C2[((size_t)n*LND + j0+s)*EDIM + eb + u0] = fv;
  }
}

// ---------------- out[i][e] = sum_j k1t[j][i]*C2[j][e] + v[i][e]; OM stored bf16 ----------------
__global__ __launch_bounds__(256) void k_out(const float* __restrict__ Z1, const float* __restrict__ C2,
                                             const u16* __restrict__ Y, u16* __restrict__ OM){
  const int ib = blockIdx.x*64, n = blockIdx.y, tid = threadIdx.x;
  __shared__ float K1s[64][68];     // [j][i_local]
  __shared__ u16 C2s[64*264];       // bf16 [j][e]
  {
    int j = tid>>2, i16 = (tid&3)*16;
    const float* zp = Z1 + ((size_t)n*LND + j)*HWN + ib + i16;
    #pragma unroll
    for(int t=0;t<16;t+=4) *(float4*)&K1s[j][i16+t] = *(const float4*)(zp+t);
    int e64 = (tid&3)*64;
    const float* cp = C2 + ((size_t)n*LND + j)*EDIM + e64;
    #pragma unroll
    for(int t=0;t<64;t+=4){
      float4 v = *(const float4*)(cp+t);
      C2s[j*264 + e64+t+0] = f2bf(v.x);
      C2s[j*264 + e64+t+1] = f2bf(v.y);
      C2s[j*264 + e64+t+2] = f2bf(v.z);
      C2s[j*264 + e64+t+3] = f2bf(v.w);
    }
  }
  __syncthreads();
  const int i0 = (tid>>4)*4, e0 = (tid&15)*16;
  float acc[4][16] = {};
  for(int j=0;j<64;j++){
    f32x4 a = *(f32x4*)&K1s[j][i0];
    const u16* cb = &C2s[j*264 + e0];
    uint4 U0 = *(const uint4*)cb;
    uint4 U1 = *(const uint4*)(cb+8);
    float bv[16];
    bf2x2(U0.x, bv[0], bv[1]);  bf2x2(U0.y, bv[2], bv[3]);
    bf2x2(U0.z, bv[4], bv[5]);  bf2x2(U0.w, bv[6], bv[7]);
    bf2x2(U1.x, bv[8], bv[9]);  bf2x2(U1.y, bv[10], bv[11]);
    bf2x2(U1.z, bv[12], bv[13]); bf2x2(U1.w, bv[14], bv[15]);
    #pragma unroll
    for(int u=0;u<16;u++){
      acc[0][u] += a[0]*bv[u];
      acc[1][u] += a[1]*bv[u];
      acc[2][u] += a[2]*bv[u];
      acc[3][u] += a[3]*bv[u];
    }
  }
  const u16* Yb = Y + (size_t)n*M3*HWN;
  u16* ob = OM + (size_t)n*HWN*EDIM;
  #pragma unroll
  for(int s=0;s<4;s++){
    int i = ib + i0 + s;
    const u16* vp = Yb + (size_t)i*M3 + 512 + e0;
    uint4 U0 = *(const uint4*)vp, U1 = *(const uint4*)(vp+8);
    float vv[16];
    bf2x2(U0.x, vv[0], vv[1]);  bf2x2(U0.y, vv[2], vv[3]);
    bf2x2(U0.z, vv[4], vv[5]);  bf2x2(U0.w, vv[6], vv[7]);
    bf2x2(U1.x, vv[8], vv[9]);  bf2x2(U1.y, vv[10], vv[11]);
    bf2x2(U1.z, vv[12], vv[13]); bf2x2(U1.w, vv[14], vv[15]);
    #pragma unroll
    for(int t=0;t<16;t+=4){
      ushort4 o;
      o.x = f2bf(acc[s][t+0]+vv[t+0]);
      o.y = f2bf(acc[s][t+1]+vv[t+1]);
      o.z = f2bf(acc[s][t+2]+vv[t+2]);
      o.w = f2bf(acc[s][t+3]+vv[t+3]);
      *(ushort4*)&ob[(size_t)i*EDIM + e0 + t] = o;
    }
  }
}

// ---------------- final proj via bf16 MFMA: out[n][co][p] = sum_e Wout[co][e]*OMflat[e][p] + b[co] ----
// grid(4 co-tiles, 64 p-tiles, 8 n); co-tile fastest so the OM tile stays L2-hot.
__global__ __launch_bounds__(256) void k_proj(const u16* __restrict__ OM, const float* __restrict__ w,
                                              const float* __restrict__ bias, float* __restrict__ out){
  const int co0 = blockIdx.x*64, p0 = blockIdx.y*64, n = blockIdx.z;
  __shared__ u16 Abf[64*KS];   // A[m=co_local][k=e]
  __shared__ u16 Bbf[64*KS];   // B^T: [n=p_local][k=e]
  const int tid = threadIdx.x;
  { // stage A: w_out rows fp32 -> bf16
    int r = tid>>2, c0 = (tid&3)*64;
    const float* wp = w + (size_t)(co0+r)*EDIM + c0;
    u16* ap = &Abf[r*KS + c0];
    #pragma unroll
    for(int t=0;t<64;t+=8){
      float4 v0 = *(const float4*)(wp+t);
      float4 v1 = *(const float4*)(wp+t+4);
      ushort4 o0, o1;
      o0.x=f2bf(v0.x); o0.y=f2bf(v0.y); o0.z=f2bf(v0.z); o0.w=f2bf(v0.w);
      o1.x=f2bf(v1.x); o1.y=f2bf(v1.y); o1.z=f2bf(v1.z); o1.w=f2bf(v1.w);
      *(ushort4*)(ap+t)   = o0;
      *(ushort4*)(ap+t+4) = o1;
    }
  }
  { // stage B transposed from bf16 OM: thread = e-row, scatter 64 p's
    const u16* op = OM + (size_t)n*HWN*EDIM + (size_t)tid*HWN + p0;
    #pragma unroll
    for(int t=0;t<64;t+=4){
      ushort4 v = *(const ushort4*)(op+t);
      Bbf[(t+0)*KS + tid] = v.x;
      Bbf[(t+1)*KS + tid] = v.y;
      Bbf[(t+2)*KS + tid] = v.z;
      Bbf[(t+3)*KS + tid] = v.w;
    }
  }
  __syncthreads();
  const int wv = tid>>6, c = tid&15, q = (tid>>4)&3;
  f32x4 acc[4];
  #pragma unroll
  for(int t=0;t<4;t++){ acc[t][0]=0.f; acc[t][1]=0.f; acc[t][2]=0.f; acc[t][3]=0.f; }
  for(int kt=0; kt<8; kt++){
    short8 a = *(const short8*)&Abf[(16*wv + c)*KS + kt*32 + q*8];
    #pragma unroll
    for(int t=0;t<4;t++){
      short8 b = *(const short8*)&Bbf[(16*t + c)*KS + kt*32 + q*8];
      acc[t] = __builtin_amdgcn_mfma_f32_16x16x32_bf16(a, b, acc[t], 0, 0, 0);
    }
  }
  float bv[4];
  #pragma unroll
  for(int r=0;r<4;r++) bv[r] = bias[co0 + 16*wv + 4*q + r];
  float* ob = out + (size_t)n*EDIM*HWN;
  #pragma unroll
  for(int t=0;t<4;t++)
    #pragma unroll
    for(int r=0;r<4;r++){
      int row = 16*wv + 4*q + r, col = 16*t + c;
      ob[(size_t)(co0+row)*HWN + p0 + col] = acc[t][r] + bv[r];
    }
}

extern "C" void kernel_launch(void* const* d_in, const int* in_sizes, int n_in,
                              void* d_out, int out_size, void* d_ws, size_t ws_size,
                              hipStream_t stream){
  (void)out_size; (void)ws_size;
  const float* x     = (const float*)d_in[0];
  const float* w_qkv = (const float*)d_in[1];
  const float* b_qkv = (const float*)d_in[2];
  const float* w_out = (const float*)d_in[3];
  const float* b_out = (const float*)d_in[4];
  for(int i=0;i<n_in;i++){
    switch(in_sizes[i]){
      case 8388608: x     = (const float*)d_in[i]; break;  // 8*256*64*64
      case 196608:  w_qkv = (const float*)d_in[i]; break;  // 768*256
      case 768:     b_qkv = (const float*)d_in[i]; break;
      case 65536:   w_out = (const float*)d_in[i]; break;  // 256*256
      case 256:     b_out = (const float*)d_in[i]; break;
      default: break;
    }
  }
  float* out = (float*)d_out;
  char* ws = (char*)d_ws;

  u16*   Y     = (u16*)(ws + 0);              // 50,331,648 B  bf16 [8][768*4096]
  float* qland = (float*)(ws + 50331648);     //    524,288 B
  float* kland = (float*)(ws + 50855936);     //    524,288 B
  float* Z1    = (float*)(ws + 51380224);     //  8,388,608 B  [8][64][4096]
  float* Z3    = (float*)(ws + 59768832);     //  8,388,608 B  [8][64][4096]
  float* KinvT = (float*)(ws + 68157440);     //    131,072 B  [8][64][64]
  float* part  = (float*)(ws + 68288512);     // 16,777,216 B  [8][32][64][256]
  float* B3    = (float*)(ws + 85065728);     //    524,288 B
  float* C2    = (float*)(ws + 85590016);     //    524,288 B
  u16*   OM    = (u16*)(ws + 86114304);       // 16,777,216 B  bf16 [8][4096*256]

  k_qkv    <<<dim3(12,64,8), 256, 0, stream>>>(x, w_qkv, b_qkv, Y);
  k_land   <<<dim3(64,8),    256, 0, stream>>>(Y, qland, kland);
  k_landgemm<<<dim3(64,16),  256, 0, stream>>>(Y, qland, kland, Z1, Z3);
  k_soft1  <<<dim3(512),     256, 0, stream>>>(Z1);
  k_soft3  <<<dim3(16,8),    256, 0, stream>>>(Z3);
  k_ns     <<<dim3(8),       256, 0, stream>>>(qland, kland, KinvT);
  k_f      <<<dim3(32,8),    256, 0, stream>>>(Z3, Y, part);
  k_fred   <<<dim3(512),     256, 0, stream>>>(part, B3);
  k_c2     <<<dim3(4,8),     256, 0, stream>>>(KinvT, B3, C2);
  k_out    <<<dim3(64,8),    256, 0, stream>>>(Z1, C2, Y, OM);
  k_proj   <<<dim3(4,64,8),  256, 0, stream>>>(OM, w_out, b_out, out);
}